// Round 11
// baseline (289.672 us; speedup 1.0000x reference)
//
#include <hip/hip_runtime.h>
#include <hip/hip_fp8.h>

#define NUSERS 100000
#define NITEMS 50000
#define NNODES 150000
#define DIM 64
#define E0 600000
#define E2 (2 * E0)
#define BB 8192
#define LW 1e-4f
#define NN16 150016
#define NB 586      // cdiv(NNODES, 256)
#define LOSS_BLOCKS 256
#define UBLK 6250   // cdiv(NUSERS, 16)  (16 nodes per 512-thr block)
#define IBLK 3125   // cdiv(NITEMS, 16)
#define PLACE_B 2344  // cdiv(E0, 256)
#define CAST_B 9375   // cdiv(NNODES*16, 256)
#define SCALE8 32.0f           // pre-scale keeps e4m3 values out of subnormals
#define ISCALE8 (1.0f / 32.0f)

// ---- bf16 helpers ----
__device__ __forceinline__ float bf_lo(unsigned u) { return __uint_as_float(u << 16); }
__device__ __forceinline__ float bf_hi(unsigned u) { return __uint_as_float(u & 0xffff0000u); }
__device__ __forceinline__ unsigned rne16(float x) {
  unsigned u = __float_as_uint(x);
  return (u + 0x7fffu + ((u >> 16) & 1u)) >> 16;
}
__device__ __forceinline__ unsigned pack2(float lo, float hi) {
  return rne16(lo) | (rne16(hi) << 16);
}

// ---- fp8 e4m3 (OCP) helpers ----
// decode: place s at bit31, e:m at bits 26..20, then scale by 2^120
// (fp8 normal (1+m/8)*2^(e-7) and subnormal m/8*2^-6 both map exactly).
__device__ __forceinline__ float f8f(unsigned b) {
  return __uint_as_float(((b & 0x80u) << 24) | ((b & 0x7fu) << 20)) * 0x1p+120f;
}
__device__ __forceinline__ unsigned f8(float x) {
  __hip_fp8_e4m3 t(x);  // RNE + saturate, HW cvt on gfx950
  return (unsigned)t.__x;
}
__device__ __forceinline__ unsigned pk4(float a, float b, float c, float d) {
  return f8(a) | (f8(b) << 8) | (f8(c) << 16) | (f8(d) << 24);
}
__device__ __forceinline__ void upk8(uint2 v, float (&a)[8]) {
  a[0] += f8f(v.x & 255u); a[1] += f8f((v.x >> 8) & 255u);
  a[2] += f8f((v.x >> 16) & 255u); a[3] += f8f(v.x >> 24);
  a[4] += f8f(v.y & 255u); a[5] += f8f((v.y >> 8) & 255u);
  a[6] += f8f((v.y >> 16) & 255u); a[7] += f8f(v.y >> 24);
}

// Degree count; atomic return value IS the edge's rank within its row.
// ~51us floor: 1.2M device-scope returning atomics (~23.5 Gop/s at the
// fabric coherence point). Sharding (R8) proven NOT to help.
__global__ void k_count_deg(const int* __restrict__ eu, const int* __restrict__ ei,
                            int* __restrict__ deg, int* __restrict__ ru,
                            int* __restrict__ ri) {
  int e = blockIdx.x * blockDim.x + threadIdx.x;
  if (e < E0) {
    ru[e] = atomicAdd(&deg[eu[e]], 1);
    ri[e] = atomicAdd(&deg[NUSERS + ei[e]], 1);
  }
}

// Scan pass 1: block-local exclusive scan of deg -> ptr, block sums -> blk.
__global__ void k_scan1(const int* __restrict__ deg, int* __restrict__ ptr,
                        int* __restrict__ blk) {
  __shared__ int s[256];
  int g = blockIdx.x * 256 + threadIdx.x;
  int v = (g < NNODES) ? deg[g] : 0;
  s[threadIdx.x] = v;
  __syncthreads();
  for (int off = 1; off < 256; off <<= 1) {
    int t = 0;
    if ((int)threadIdx.x >= off) t = s[threadIdx.x - off];
    __syncthreads();
    if ((int)threadIdx.x >= off) s[threadIdx.x] += t;
    __syncthreads();
  }
  if (g < NNODES) ptr[g] = s[threadIdx.x] - v;
  if (threadIdx.x == 255) blk[blockIdx.x] = s[255];
}

// Fused scan fixup: redundant predecessor block-sum reduce + ptr fixup + dinv.
__global__ void k_scan_fix(int* __restrict__ ptr, const int* __restrict__ blk,
                           const int* __restrict__ deg, float* __restrict__ dinv) {
  __shared__ int swsum[4];
  __shared__ int sPre;
  int tid = threadIdx.x;
  int part = 0;
  for (int j = tid; j < (int)blockIdx.x; j += 256) part += blk[j];
  for (int off = 32; off > 0; off >>= 1) part += __shfl_down(part, off);
  if ((tid & 63) == 0) swsum[tid >> 6] = part;
  __syncthreads();
  if (tid == 0) sPre = swsum[0] + swsum[1] + swsum[2] + swsum[3];
  __syncthreads();
  int g = blockIdx.x * 256 + tid;
  if (g < NNODES) {
    ptr[g] += sPre;
    int d = deg[g];
    dinv[g] = d > 0 ? rsqrtf((float)d) : 0.0f;
  }
}

// Fused: CSR placement (no atomics) + scaled fp8 cast s0 = SCALE8*dinv*x.
// Cast blocks fill CUs underneath place's latency-bound scattered stores.
__global__ void k_place_cast(const int* __restrict__ eu, const int* __restrict__ ei,
                             const int* __restrict__ ptr, const int* __restrict__ ru,
                             const int* __restrict__ ri, int* __restrict__ col,
                             const float4* __restrict__ Gu4, const float4* __restrict__ Gi4,
                             const float* __restrict__ dinv, unsigned* __restrict__ h0) {
  int b = blockIdx.x;
  if (b < PLACE_B) {
    int e = b * 256 + threadIdx.x;
    if (e < E0) {
      int u = eu[e];
      int it = NUSERS + ei[e];
      col[ptr[u] + ru[e]] = it;
      col[ptr[it] + ri[e]] = u;
    }
  } else {
    int t = (b - PLACE_B) * 256 + threadIdx.x;
    if (t < NNODES * 16) {
      int node = t >> 4;
      float dv = dinv[node] * SCALE8;
      float4 v = (t < NUSERS * 16) ? Gu4[t] : Gi4[t - NUSERS * 16];
      h0[t] = pk4(dv * v.x, dv * v.y, dv * v.z, dv * v.w);
    }
  }
}

// Scaled-space SpMM, fp8 input rows (64 B = 1 cache line per gather).
// s_out(n) = (1/deg(n)) * sum_c s_in(c). 2 nodes/wave; lane = 8*sub + q.
// OUT8: write fp8 (layer 1) or bf16 (layer 2).
template <bool OUT8>
__global__ __launch_bounds__(512) void k_spmm2(
    const int* __restrict__ ptr, const int* __restrict__ deg,
    const int* __restrict__ col, const float* __restrict__ dinv,
    const uint2* __restrict__ h, void* __restrict__ houtv) {
  int wid = threadIdx.x >> 6;
  int lane = threadIdx.x & 63;
  int sub = lane >> 3;
  int q = lane & 7;
  int gA, coff;
  if (blockIdx.x < UBLK) {           // user dst gather from item half
    gA = blockIdx.x * 16 + wid * 2;
    coff = NUSERS;
  } else {                            // item dst gather from user half
    gA = NUSERS + (blockIdx.x - UBLK) * 16 + wid * 2;
    coff = 0;
  }
  const uint2* hsrc = h + (size_t)coff * 8;
  int gB = gA + 1;
  int stA = ptr[gA], dgA = deg[gA];
  int stB = ptr[gB], dgB = deg[gB];
  float dnA = dinv[gA], dnB = dinv[gB];
  float aA[8] = {0, 0, 0, 0, 0, 0, 0, 0};
  float aB[8] = {0, 0, 0, 0, 0, 0, 0, 0};
  for (int j = stA + sub; j < stA + dgA; j += 8) {
    int c = col[j];
    upk8(hsrc[(size_t)(c - coff) * 8 + q], aA);
  }
  for (int j = stB + sub; j < stB + dgB; j += 8) {
    int c = col[j];
    upk8(hsrc[(size_t)(c - coff) * 8 + q], aB);
  }
  #pragma unroll
  for (int m = 8; m <= 32; m <<= 1) {
    #pragma unroll
    for (int k = 0; k < 8; ++k) {
      aA[k] += __shfl_xor(aA[k], m);
      aB[k] += __shfl_xor(aB[k], m);
    }
  }
  if (sub == 0) {
    float sA = dnA * dnA;
    float sB = dnB * dnB;
    if (OUT8) {
      uint2* ho = (uint2*)houtv;
      ho[(size_t)gA * 8 + q] = make_uint2(pk4(aA[0] * sA, aA[1] * sA, aA[2] * sA, aA[3] * sA),
                                          pk4(aA[4] * sA, aA[5] * sA, aA[6] * sA, aA[7] * sA));
      ho[(size_t)gB * 8 + q] = make_uint2(pk4(aB[0] * sB, aB[1] * sB, aB[2] * sB, aB[3] * sB),
                                          pk4(aB[4] * sB, aB[5] * sB, aB[6] * sB, aB[7] * sB));
    } else {
      uint4* ho = (uint4*)houtv;
      ho[(size_t)gA * 8 + q] = make_uint4(pack2(aA[0] * sA, aA[1] * sA), pack2(aA[2] * sA, aA[3] * sA),
                                          pack2(aA[4] * sA, aA[5] * sA), pack2(aA[6] * sA, aA[7] * sA));
      ho[(size_t)gB * 8 + q] = make_uint4(pack2(aB[0] * sB, aB[1] * sB), pack2(aB[2] * sB, aB[3] * sB),
                                          pack2(aB[4] * sB, aB[5] * sB), pack2(aB[6] * sB, aB[7] * sB));
    }
  }
}

__device__ __forceinline__ int decode_node(int k, const int* __restrict__ usr,
                                           const int* __restrict__ pos,
                                           const int* __restrict__ neg, int* coff) {
  if (k < BB) { *coff = NUSERS; return usr[k]; }
  if (k < 2 * BB) { *coff = 0; return NUSERS + pos[k - BB]; }
  *coff = 0; return NUSERS + neg[k - 2 * BB];
}

// Layer-3 SpMM only at the <=3*BB batch nodes (bf16 in h2 -> bf16 h3).
__global__ __launch_bounds__(512) void k_spmm_batch(
    const int* __restrict__ usr, const int* __restrict__ pos, const int* __restrict__ neg,
    const int* __restrict__ ptr, const int* __restrict__ deg,
    const int* __restrict__ col, const float* __restrict__ dinv,
    const uint4* __restrict__ h, uint4* __restrict__ hout) {
  int wid = threadIdx.x >> 6;
  int lane = threadIdx.x & 63;
  int sub = lane >> 3;
  int q = lane & 7;
  int k0 = blockIdx.x * 16 + wid * 2;
  int cofA, cofB;
  int gA = decode_node(k0, usr, pos, neg, &cofA);
  int gB = decode_node(k0 + 1, usr, pos, neg, &cofB);
  const uint4* hsA = h + (size_t)cofA * 8;
  const uint4* hsB = h + (size_t)cofB * 8;
  int stA = ptr[gA], dgA = deg[gA];
  int stB = ptr[gB], dgB = deg[gB];
  float dnA = dinv[gA], dnB = dinv[gB];
  float aA0 = 0, aA1 = 0, aA2 = 0, aA3 = 0, aA4 = 0, aA5 = 0, aA6 = 0, aA7 = 0;
  float aB0 = 0, aB1 = 0, aB2 = 0, aB3 = 0, aB4 = 0, aB5 = 0, aB6 = 0, aB7 = 0;
  for (int j = stA + sub; j < stA + dgA; j += 8) {
    int c = col[j];
    uint4 x = hsA[(size_t)(c - cofA) * 8 + q];
    aA0 += bf_lo(x.x); aA1 += bf_hi(x.x); aA2 += bf_lo(x.y); aA3 += bf_hi(x.y);
    aA4 += bf_lo(x.z); aA5 += bf_hi(x.z); aA6 += bf_lo(x.w); aA7 += bf_hi(x.w);
  }
  for (int j = stB + sub; j < stB + dgB; j += 8) {
    int c = col[j];
    uint4 x = hsB[(size_t)(c - cofB) * 8 + q];
    aB0 += bf_lo(x.x); aB1 += bf_hi(x.x); aB2 += bf_lo(x.y); aB3 += bf_hi(x.y);
    aB4 += bf_lo(x.z); aB5 += bf_hi(x.z); aB6 += bf_lo(x.w); aB7 += bf_hi(x.w);
  }
  #pragma unroll
  for (int m = 8; m <= 32; m <<= 1) {
    aA0 += __shfl_xor(aA0, m); aA1 += __shfl_xor(aA1, m);
    aA2 += __shfl_xor(aA2, m); aA3 += __shfl_xor(aA3, m);
    aA4 += __shfl_xor(aA4, m); aA5 += __shfl_xor(aA5, m);
    aA6 += __shfl_xor(aA6, m); aA7 += __shfl_xor(aA7, m);
    aB0 += __shfl_xor(aB0, m); aB1 += __shfl_xor(aB1, m);
    aB2 += __shfl_xor(aB2, m); aB3 += __shfl_xor(aB3, m);
    aB4 += __shfl_xor(aB4, m); aB5 += __shfl_xor(aB5, m);
    aB6 += __shfl_xor(aB6, m); aB7 += __shfl_xor(aB7, m);
  }
  if (sub == 0) {
    float sA = dnA * dnA;
    float sB = dnB * dnB;
    hout[(size_t)gA * 8 + q] = make_uint4(pack2(aA0 * sA, aA1 * sA), pack2(aA2 * sA, aA3 * sA),
                                          pack2(aA4 * sA, aA5 * sA), pack2(aA6 * sA, aA7 * sA));
    hout[(size_t)gB * 8 + q] = make_uint4(pack2(aB0 * sB, aB1 * sB), pack2(aB2 * sB, aB3 * sB),
                                          pack2(aB4 * sB, aB5 * sB), pack2(aB6 * sB, aB7 * sB));
  }
}

// Fused batch gather + layer sum + BPR loss + last-block final reduce.
// h1 is fp8 (SCALE8*s1); h2,h3 bf16 (SCALE8*s2, SCALE8*s3).
__global__ void k_loss(const int* __restrict__ usr, const int* __restrict__ pos,
                       const int* __restrict__ neg, const int* __restrict__ deg,
                       const float4* __restrict__ Gu4, const float4* __restrict__ Gi4,
                       const unsigned* __restrict__ h1, const uint2* __restrict__ h2,
                       const uint2* __restrict__ h3, float* __restrict__ bpart,
                       int* __restrict__ cnt, float* __restrict__ out) {
  __shared__ float sL[4], sR[4];
  __shared__ int sDone;
  int wid = threadIdx.x >> 6;
  int lane = threadIdx.x & 63;
  int r = lane >> 4;
  int q = lane & 15;
  int gw = blockIdx.x * 4 + wid;
  int nw = gridDim.x * 4;
  const float s = 0.25f;
  float accL = 0.0f, accR = 0.0f;
  for (int b4 = gw; b4 < BB / 4; b4 += nw) {
    int b = b4 * 4 + r;
    int iu = usr[b], ip = pos[b], ig = neg[b];
    float sdu = sqrtf((float)deg[iu]) * ISCALE8;
    float sdp = sqrtf((float)deg[NUSERS + ip]) * ISCALE8;
    float sdn = sqrtf((float)deg[NUSERS + ig]) * ISCALE8;
    size_t ou = (size_t)iu * 16 + q;
    size_t op = ((size_t)NUSERS + ip) * 16 + q;
    size_t on = ((size_t)NUSERS + ig) * 16 + q;
    float4 u = Gu4[ou];
    float4 p = Gi4[(size_t)ip * 16 + q];
    float4 g = Gi4[(size_t)ig * 16 + q];
    float4 su = {0, 0, 0, 0}, sp = {0, 0, 0, 0}, sg = {0, 0, 0, 0};
    unsigned w;
    uint2 v;
    w = h1[ou]; su.x += f8f(w & 255u); su.y += f8f((w >> 8) & 255u);
                su.z += f8f((w >> 16) & 255u); su.w += f8f(w >> 24);
    v = h2[ou]; su.x += bf_lo(v.x); su.y += bf_hi(v.x); su.z += bf_lo(v.y); su.w += bf_hi(v.y);
    v = h3[ou]; su.x += bf_lo(v.x); su.y += bf_hi(v.x); su.z += bf_lo(v.y); su.w += bf_hi(v.y);
    w = h1[op]; sp.x += f8f(w & 255u); sp.y += f8f((w >> 8) & 255u);
                sp.z += f8f((w >> 16) & 255u); sp.w += f8f(w >> 24);
    v = h2[op]; sp.x += bf_lo(v.x); sp.y += bf_hi(v.x); sp.z += bf_lo(v.y); sp.w += bf_hi(v.y);
    v = h3[op]; sp.x += bf_lo(v.x); sp.y += bf_hi(v.x); sp.z += bf_lo(v.y); sp.w += bf_hi(v.y);
    w = h1[on]; sg.x += f8f(w & 255u); sg.y += f8f((w >> 8) & 255u);
                sg.z += f8f((w >> 16) & 255u); sg.w += f8f(w >> 24);
    v = h2[on]; sg.x += bf_lo(v.x); sg.y += bf_hi(v.x); sg.z += bf_lo(v.y); sg.w += bf_hi(v.y);
    v = h3[on]; sg.x += bf_lo(v.x); sg.y += bf_hi(v.x); sg.z += bf_lo(v.y); sg.w += bf_hi(v.y);
    u.x = (u.x + sdu * su.x) * s; u.y = (u.y + sdu * su.y) * s;
    u.z = (u.z + sdu * su.z) * s; u.w = (u.w + sdu * su.w) * s;
    p.x = (p.x + sdp * sp.x) * s; p.y = (p.y + sdp * sp.y) * s;
    p.z = (p.z + sdp * sp.z) * s; p.w = (p.w + sdp * sp.w) * s;
    g.x = (g.x + sdn * sg.x) * s; g.y = (g.y + sdn * sg.y) * s;
    g.z = (g.z + sdn * sg.z) * s; g.w = (g.w + sdn * sg.w) * s;
    float dp = u.x * p.x + u.y * p.y + u.z * p.z + u.w * p.w;
    float dn = u.x * g.x + u.y * g.y + u.z * g.z + u.w * g.w;
    float rg = u.x * u.x + u.y * u.y + u.z * u.z + u.w * u.w
             + p.x * p.x + p.y * p.y + p.z * p.z + p.w * p.w
             + g.x * g.x + g.y * g.y + g.z * g.z + g.w * g.w;
    #pragma unroll
    for (int m = 1; m <= 8; m <<= 1) {
      dp += __shfl_xor(dp, m);
      dn += __shfl_xor(dn, m);
      rg += __shfl_xor(rg, m);
    }
    if (q == 0) {
      float diff = dp - dn;
      accL -= fminf(diff, 0.0f) - log1pf(expf(-fabsf(diff)));
      accR += rg;
    }
  }
  accL += __shfl_xor(accL, 16); accR += __shfl_xor(accR, 16);
  accL += __shfl_xor(accL, 32); accR += __shfl_xor(accR, 32);
  if (lane == 0) { sL[wid] = accL; sR[wid] = accR; }
  __syncthreads();
  if (threadIdx.x == 0) {
    bpart[blockIdx.x] = sL[0] + sL[1] + sL[2] + sL[3];
    bpart[LOSS_BLOCKS + blockIdx.x] = sR[0] + sR[1] + sR[2] + sR[3];
    __threadfence();
    sDone = (atomicAdd(cnt, 1) == LOSS_BLOCKS - 1) ? 1 : 0;
  }
  __syncthreads();
  if (sDone && threadIdx.x < 64) {
    __threadfence();  // acquire: other blocks' bpart stores
    int ln = threadIdx.x;
    float l = bpart[ln] + bpart[ln + 64] + bpart[ln + 128] + bpart[ln + 192];
    float rr = bpart[LOSS_BLOCKS + ln] + bpart[LOSS_BLOCKS + ln + 64]
             + bpart[LOSS_BLOCKS + ln + 128] + bpart[LOSS_BLOCKS + ln + 192];
    for (int off = 32; off > 0; off >>= 1) {
      l += __shfl_down(l, off);
      rr += __shfl_down(rr, off);
    }
    if (ln == 0) out[0] = l * (1.0f / BB) + LW * 0.5f * rr * (1.0f / BB);
  }
}

extern "C" void kernel_launch(void* const* d_in, const int* in_sizes, int n_in,
                              void* d_out, int out_size, void* d_ws, size_t ws_size,
                              hipStream_t stream) {
  const float* Gu = (const float*)d_in[0];
  const float* Gi = (const float*)d_in[1];
  const int* eu  = (const int*)d_in[2];
  const int* ei  = (const int*)d_in[3];
  const int* usr = (const int*)d_in[4];
  const int* pos = (const int*)d_in[5];
  const int* neg = (const int*)d_in[6];
  float* out = (float*)d_out;

  // Workspace: ~8 MB ints + 9.6+9.6+19.2+19.2 MB h = ~66 MB.
  int* deg   = (int*)d_ws;                 // NN16
  int* cnt   = deg + NN16;                 // 16 (zeroed with deg via memset)
  int* ptr   = cnt + 16;                   // NN16
  int* blk   = ptr + NN16;                 // 1024
  int* ru    = blk + 1024;                 // E0
  int* ri    = ru + E0;                    // E0
  int* col   = ri + E0;                    // E2
  float* dinv = (float*)(col + E2);        // NN16
  unsigned* h0 = (unsigned*)(dinv + NN16); // NNODES*16 uints (fp8, 9.6 MB)
  unsigned* h1 = h0 + (size_t)NNODES * 16; // fp8, 9.6 MB
  uint2* h2  = (uint2*)(h1 + (size_t)NNODES * 16);  // bf16, 19.2 MB
  uint2* h3  = h2 + (size_t)NNODES * 16;            // bf16, 19.2 MB
  float* bpart = (float*)(h3 + (size_t)NNODES * 16);  // 2*LOSS_BLOCKS

  const int T = 256;
  auto cdiv = [](int a, int b) { return (a + b - 1) / b; };

  const float4* Gu4 = (const float4*)Gu;
  const float4* Gi4 = (const float4*)Gi;

  hipMemsetAsync(deg, 0, (size_t)(NN16 + 16) * sizeof(int), stream);
  k_count_deg<<<cdiv(E0, T), T, 0, stream>>>(eu, ei, deg, ru, ri);
  k_scan1<<<NB, 256, 0, stream>>>(deg, ptr, blk);
  k_scan_fix<<<NB, 256, 0, stream>>>(ptr, blk, deg, dinv);
  k_place_cast<<<PLACE_B + CAST_B, 256, 0, stream>>>(eu, ei, ptr, ru, ri, col,
                                                     Gu4, Gi4, dinv, h0);

  k_spmm2<true><<<UBLK + IBLK, 512, 0, stream>>>(ptr, deg, col, dinv,
                                                 (const uint2*)h0, (void*)h1);
  k_spmm2<false><<<UBLK + IBLK, 512, 0, stream>>>(ptr, deg, col, dinv,
                                                  (const uint2*)h1, (void*)h2);
  k_spmm_batch<<<(3 * BB) / 16, 512, 0, stream>>>(usr, pos, neg, ptr, deg, col, dinv,
                                                  (const uint4*)h2, (uint4*)h3);

  k_loss<<<LOSS_BLOCKS, 256, 0, stream>>>(usr, pos, neg, deg, Gu4, Gi4,
                                          h1, h2, h3, bpart, cnt, out);
}

// Round 12
// 278.666 us; speedup vs baseline: 1.0395x; 1.0395x over previous
//
#include <hip/hip_runtime.h>
#include <hip/hip_fp8.h>

#define NUSERS 100000
#define NITEMS 50000
#define NNODES 150000
#define DIM 64
#define E0 600000
#define E2 (2 * E0)
#define BB 8192
#define LW 1e-4f
#define NN16 150016
#define NB 586      // cdiv(NNODES, 256)
#define LOSS_BLOCKS 256
#define UBLK 6250   // cdiv(NUSERS, 16)  (16 nodes per 512-thr block)
#define IBLK 3125   // cdiv(NITEMS, 16)
#define PLACE_B 2344  // cdiv(E0, 256)
#define CAST_B 9375   // cdiv(NNODES*16, 256)
#define SCALE8 32.0f           // pre-scale keeps e4m3 values out of subnormals
#define ISCALE8 (1.0f / 32.0f)

typedef float floatx2 __attribute__((ext_vector_type(2)));

// ---- bf16 helpers ----
__device__ __forceinline__ float bf_lo(unsigned u) { return __uint_as_float(u << 16); }
__device__ __forceinline__ float bf_hi(unsigned u) { return __uint_as_float(u & 0xffff0000u); }
__device__ __forceinline__ unsigned rne16(float x) {
  unsigned u = __float_as_uint(x);
  return (u + 0x7fffu + ((u >> 16) & 1u)) >> 16;
}
__device__ __forceinline__ unsigned pack2(float lo, float hi) {
  return rne16(lo) | (rne16(hi) << 16);
}

// ---- fp8 e4m3 (OCP) helpers — HW converters (v_cvt_pk_*_fp8) ----
#if __has_builtin(__builtin_amdgcn_cvt_pk_f32_fp8) && __has_builtin(__builtin_amdgcn_cvt_pk_fp8_f32)
#define FP8_HW 1
#else
#define FP8_HW 0
#endif

__device__ __forceinline__ float f8f_sw(unsigned b) {
  return __uint_as_float(((b & 0x80u) << 24) | ((b & 0x7fu) << 20)) * 0x1p+120f;
}

// decode 4 fp8 bytes in a uint -> f[0..3] added
__device__ __forceinline__ void upk4(unsigned w, float* f) {
#if FP8_HW
  floatx2 lo = __builtin_amdgcn_cvt_pk_f32_fp8((int)w, false);
  floatx2 hi = __builtin_amdgcn_cvt_pk_f32_fp8((int)w, true);
  f[0] += lo.x; f[1] += lo.y; f[2] += hi.x; f[3] += hi.y;
#else
  f[0] += f8f_sw(w & 255u); f[1] += f8f_sw((w >> 8) & 255u);
  f[2] += f8f_sw((w >> 16) & 255u); f[3] += f8f_sw(w >> 24);
#endif
}

__device__ __forceinline__ void upk8(uint2 v, float (&a)[8]) {
  upk4(v.x, a);
  upk4(v.y, a + 4);
}

// encode 4 floats -> packed fp8 uint
__device__ __forceinline__ unsigned pk4(float a, float b, float c, float d) {
#if FP8_HW
  int r = __builtin_amdgcn_cvt_pk_fp8_f32(a, b, 0, false);
  r = __builtin_amdgcn_cvt_pk_fp8_f32(c, d, r, true);
  return (unsigned)r;
#else
  __hip_fp8_e4m3 ta(a), tb(b), tc(c), td(d);
  return (unsigned)ta.__x | ((unsigned)tb.__x << 8) |
         ((unsigned)tc.__x << 16) | ((unsigned)td.__x << 24);
#endif
}

// Degree count; atomic return value IS the edge's rank within its row.
// ~51us floor: 1.2M device-scope returning atomics (~23.5 Gop/s at the
// fabric coherence point). Sharding (R8) proven NOT to help.
__global__ void k_count_deg(const int* __restrict__ eu, const int* __restrict__ ei,
                            int* __restrict__ deg, int* __restrict__ ru,
                            int* __restrict__ ri) {
  int e = blockIdx.x * blockDim.x + threadIdx.x;
  if (e < E0) {
    ru[e] = atomicAdd(&deg[eu[e]], 1);
    ri[e] = atomicAdd(&deg[NUSERS + ei[e]], 1);
  }
}

// Scan pass 1: block-local exclusive scan of deg -> ptr, block sums -> blk.
__global__ void k_scan1(const int* __restrict__ deg, int* __restrict__ ptr,
                        int* __restrict__ blk) {
  __shared__ int s[256];
  int g = blockIdx.x * 256 + threadIdx.x;
  int v = (g < NNODES) ? deg[g] : 0;
  s[threadIdx.x] = v;
  __syncthreads();
  for (int off = 1; off < 256; off <<= 1) {
    int t = 0;
    if ((int)threadIdx.x >= off) t = s[threadIdx.x - off];
    __syncthreads();
    if ((int)threadIdx.x >= off) s[threadIdx.x] += t;
    __syncthreads();
  }
  if (g < NNODES) ptr[g] = s[threadIdx.x] - v;
  if (threadIdx.x == 255) blk[blockIdx.x] = s[255];
}

// Fused scan fixup: redundant predecessor block-sum reduce + ptr fixup + dinv.
__global__ void k_scan_fix(int* __restrict__ ptr, const int* __restrict__ blk,
                           const int* __restrict__ deg, float* __restrict__ dinv) {
  __shared__ int swsum[4];
  __shared__ int sPre;
  int tid = threadIdx.x;
  int part = 0;
  for (int j = tid; j < (int)blockIdx.x; j += 256) part += blk[j];
  for (int off = 32; off > 0; off >>= 1) part += __shfl_down(part, off);
  if ((tid & 63) == 0) swsum[tid >> 6] = part;
  __syncthreads();
  if (tid == 0) sPre = swsum[0] + swsum[1] + swsum[2] + swsum[3];
  __syncthreads();
  int g = blockIdx.x * 256 + tid;
  if (g < NNODES) {
    ptr[g] += sPre;
    int d = deg[g];
    dinv[g] = d > 0 ? rsqrtf((float)d) : 0.0f;
  }
}

// Fused: CSR placement (no atomics) + scaled fp8 cast s0 = SCALE8*dinv*x.
// Cast blocks fill CUs underneath place's latency-bound scattered stores.
__global__ void k_place_cast(const int* __restrict__ eu, const int* __restrict__ ei,
                             const int* __restrict__ ptr, const int* __restrict__ ru,
                             const int* __restrict__ ri, int* __restrict__ col,
                             const float4* __restrict__ Gu4, const float4* __restrict__ Gi4,
                             const float* __restrict__ dinv, unsigned* __restrict__ h0) {
  int b = blockIdx.x;
  if (b < PLACE_B) {
    int e = b * 256 + threadIdx.x;
    if (e < E0) {
      int u = eu[e];
      int it = NUSERS + ei[e];
      col[ptr[u] + ru[e]] = it;
      col[ptr[it] + ri[e]] = u;
    }
  } else {
    int t = (b - PLACE_B) * 256 + threadIdx.x;
    if (t < NNODES * 16) {
      int node = t >> 4;
      float dv = dinv[node] * SCALE8;
      float4 v = (t < NUSERS * 16) ? Gu4[t] : Gi4[t - NUSERS * 16];
      h0[t] = pk4(dv * v.x, dv * v.y, dv * v.z, dv * v.w);
    }
  }
}

// Scaled-space SpMM, fp8 input rows (64 B = 1 cache line per gather).
// s_out(n) = dinv(n)^2 * sum_c s_in(c). 2 nodes/wave; lane = 8*sub + q.
// OUT8: write fp8 (layer 1) or bf16 (layer 2).
template <bool OUT8>
__global__ __launch_bounds__(512) void k_spmm2(
    const int* __restrict__ ptr, const int* __restrict__ deg,
    const int* __restrict__ col, const float* __restrict__ dinv,
    const uint2* __restrict__ h, void* __restrict__ houtv) {
  int wid = threadIdx.x >> 6;
  int lane = threadIdx.x & 63;
  int sub = lane >> 3;
  int q = lane & 7;
  int gA, coff;
  if (blockIdx.x < UBLK) {           // user dst gather from item half
    gA = blockIdx.x * 16 + wid * 2;
    coff = NUSERS;
  } else {                            // item dst gather from user half
    gA = NUSERS + (blockIdx.x - UBLK) * 16 + wid * 2;
    coff = 0;
  }
  const uint2* hsrc = h + (size_t)coff * 8;
  int gB = gA + 1;
  int stA = ptr[gA], dgA = deg[gA];
  int stB = ptr[gB], dgB = deg[gB];
  float dnA = dinv[gA], dnB = dinv[gB];
  float aA[8] = {0, 0, 0, 0, 0, 0, 0, 0};
  float aB[8] = {0, 0, 0, 0, 0, 0, 0, 0};
  for (int j = stA + sub; j < stA + dgA; j += 8) {
    int c = col[j];
    upk8(hsrc[(size_t)(c - coff) * 8 + q], aA);
  }
  for (int j = stB + sub; j < stB + dgB; j += 8) {
    int c = col[j];
    upk8(hsrc[(size_t)(c - coff) * 8 + q], aB);
  }
  #pragma unroll
  for (int m = 8; m <= 32; m <<= 1) {
    #pragma unroll
    for (int k = 0; k < 8; ++k) {
      aA[k] += __shfl_xor(aA[k], m);
      aB[k] += __shfl_xor(aB[k], m);
    }
  }
  if (sub == 0) {
    float sA = dnA * dnA;
    float sB = dnB * dnB;
    if (OUT8) {
      uint2* ho = (uint2*)houtv;
      ho[(size_t)gA * 8 + q] = make_uint2(pk4(aA[0] * sA, aA[1] * sA, aA[2] * sA, aA[3] * sA),
                                          pk4(aA[4] * sA, aA[5] * sA, aA[6] * sA, aA[7] * sA));
      ho[(size_t)gB * 8 + q] = make_uint2(pk4(aB[0] * sB, aB[1] * sB, aB[2] * sB, aB[3] * sB),
                                          pk4(aB[4] * sB, aB[5] * sB, aB[6] * sB, aB[7] * sB));
    } else {
      uint4* ho = (uint4*)houtv;
      ho[(size_t)gA * 8 + q] = make_uint4(pack2(aA[0] * sA, aA[1] * sA), pack2(aA[2] * sA, aA[3] * sA),
                                          pack2(aA[4] * sA, aA[5] * sA), pack2(aA[6] * sA, aA[7] * sA));
      ho[(size_t)gB * 8 + q] = make_uint4(pack2(aB[0] * sB, aB[1] * sB), pack2(aB[2] * sB, aB[3] * sB),
                                          pack2(aB[4] * sB, aB[5] * sB), pack2(aB[6] * sB, aB[7] * sB));
    }
  }
}

__device__ __forceinline__ int decode_node(int k, const int* __restrict__ usr,
                                           const int* __restrict__ pos,
                                           const int* __restrict__ neg, int* coff) {
  if (k < BB) { *coff = NUSERS; return usr[k]; }
  if (k < 2 * BB) { *coff = 0; return NUSERS + pos[k - BB]; }
  *coff = 0; return NUSERS + neg[k - 2 * BB];
}

// Layer-3 SpMM only at the <=3*BB batch nodes (bf16 in h2 -> bf16 h3).
__global__ __launch_bounds__(512) void k_spmm_batch(
    const int* __restrict__ usr, const int* __restrict__ pos, const int* __restrict__ neg,
    const int* __restrict__ ptr, const int* __restrict__ deg,
    const int* __restrict__ col, const float* __restrict__ dinv,
    const uint4* __restrict__ h, uint4* __restrict__ hout) {
  int wid = threadIdx.x >> 6;
  int lane = threadIdx.x & 63;
  int sub = lane >> 3;
  int q = lane & 7;
  int k0 = blockIdx.x * 16 + wid * 2;
  int cofA, cofB;
  int gA = decode_node(k0, usr, pos, neg, &cofA);
  int gB = decode_node(k0 + 1, usr, pos, neg, &cofB);
  const uint4* hsA = h + (size_t)cofA * 8;
  const uint4* hsB = h + (size_t)cofB * 8;
  int stA = ptr[gA], dgA = deg[gA];
  int stB = ptr[gB], dgB = deg[gB];
  float dnA = dinv[gA], dnB = dinv[gB];
  float aA0 = 0, aA1 = 0, aA2 = 0, aA3 = 0, aA4 = 0, aA5 = 0, aA6 = 0, aA7 = 0;
  float aB0 = 0, aB1 = 0, aB2 = 0, aB3 = 0, aB4 = 0, aB5 = 0, aB6 = 0, aB7 = 0;
  for (int j = stA + sub; j < stA + dgA; j += 8) {
    int c = col[j];
    uint4 x = hsA[(size_t)(c - cofA) * 8 + q];
    aA0 += bf_lo(x.x); aA1 += bf_hi(x.x); aA2 += bf_lo(x.y); aA3 += bf_hi(x.y);
    aA4 += bf_lo(x.z); aA5 += bf_hi(x.z); aA6 += bf_lo(x.w); aA7 += bf_hi(x.w);
  }
  for (int j = stB + sub; j < stB + dgB; j += 8) {
    int c = col[j];
    uint4 x = hsB[(size_t)(c - cofB) * 8 + q];
    aB0 += bf_lo(x.x); aB1 += bf_hi(x.x); aB2 += bf_lo(x.y); aB3 += bf_hi(x.y);
    aB4 += bf_lo(x.z); aB5 += bf_hi(x.z); aB6 += bf_lo(x.w); aB7 += bf_hi(x.w);
  }
  #pragma unroll
  for (int m = 8; m <= 32; m <<= 1) {
    aA0 += __shfl_xor(aA0, m); aA1 += __shfl_xor(aA1, m);
    aA2 += __shfl_xor(aA2, m); aA3 += __shfl_xor(aA3, m);
    aA4 += __shfl_xor(aA4, m); aA5 += __shfl_xor(aA5, m);
    aA6 += __shfl_xor(aA6, m); aA7 += __shfl_xor(aA7, m);
    aB0 += __shfl_xor(aB0, m); aB1 += __shfl_xor(aB1, m);
    aB2 += __shfl_xor(aB2, m); aB3 += __shfl_xor(aB3, m);
    aB4 += __shfl_xor(aB4, m); aB5 += __shfl_xor(aB5, m);
    aB6 += __shfl_xor(aB6, m); aB7 += __shfl_xor(aB7, m);
  }
  if (sub == 0) {
    float sA = dnA * dnA;
    float sB = dnB * dnB;
    hout[(size_t)gA * 8 + q] = make_uint4(pack2(aA0 * sA, aA1 * sA), pack2(aA2 * sA, aA3 * sA),
                                          pack2(aA4 * sA, aA5 * sA), pack2(aA6 * sA, aA7 * sA));
    hout[(size_t)gB * 8 + q] = make_uint4(pack2(aB0 * sB, aB1 * sB), pack2(aB2 * sB, aB3 * sB),
                                          pack2(aB4 * sB, aB5 * sB), pack2(aB6 * sB, aB7 * sB));
  }
}

// Fused batch gather + layer sum + BPR loss + last-block final reduce.
// h1 is fp8 (SCALE8*s1); h2,h3 bf16 (SCALE8*s2, SCALE8*s3).
__global__ void k_loss(const int* __restrict__ usr, const int* __restrict__ pos,
                       const int* __restrict__ neg, const int* __restrict__ deg,
                       const float4* __restrict__ Gu4, const float4* __restrict__ Gi4,
                       const unsigned* __restrict__ h1, const uint2* __restrict__ h2,
                       const uint2* __restrict__ h3, float* __restrict__ bpart,
                       int* __restrict__ cnt, float* __restrict__ out) {
  __shared__ float sL[4], sR[4];
  __shared__ int sDone;
  int wid = threadIdx.x >> 6;
  int lane = threadIdx.x & 63;
  int r = lane >> 4;
  int q = lane & 15;
  int gw = blockIdx.x * 4 + wid;
  int nw = gridDim.x * 4;
  const float s = 0.25f;
  float accL = 0.0f, accR = 0.0f;
  for (int b4 = gw; b4 < BB / 4; b4 += nw) {
    int b = b4 * 4 + r;
    int iu = usr[b], ip = pos[b], ig = neg[b];
    float sdu = sqrtf((float)deg[iu]) * ISCALE8;
    float sdp = sqrtf((float)deg[NUSERS + ip]) * ISCALE8;
    float sdn = sqrtf((float)deg[NUSERS + ig]) * ISCALE8;
    size_t ou = (size_t)iu * 16 + q;
    size_t op = ((size_t)NUSERS + ip) * 16 + q;
    size_t on = ((size_t)NUSERS + ig) * 16 + q;
    float4 u = Gu4[ou];
    float4 p = Gi4[(size_t)ip * 16 + q];
    float4 g = Gi4[(size_t)ig * 16 + q];
    float su[4] = {0, 0, 0, 0}, sp[4] = {0, 0, 0, 0}, sg[4] = {0, 0, 0, 0};
    uint2 v;
    upk4(h1[ou], su);
    v = h2[ou]; su[0] += bf_lo(v.x); su[1] += bf_hi(v.x); su[2] += bf_lo(v.y); su[3] += bf_hi(v.y);
    v = h3[ou]; su[0] += bf_lo(v.x); su[1] += bf_hi(v.x); su[2] += bf_lo(v.y); su[3] += bf_hi(v.y);
    upk4(h1[op], sp);
    v = h2[op]; sp[0] += bf_lo(v.x); sp[1] += bf_hi(v.x); sp[2] += bf_lo(v.y); sp[3] += bf_hi(v.y);
    v = h3[op]; sp[0] += bf_lo(v.x); sp[1] += bf_hi(v.x); sp[2] += bf_lo(v.y); sp[3] += bf_hi(v.y);
    upk4(h1[on], sg);
    v = h2[on]; sg[0] += bf_lo(v.x); sg[1] += bf_hi(v.x); sg[2] += bf_lo(v.y); sg[3] += bf_hi(v.y);
    v = h3[on]; sg[0] += bf_lo(v.x); sg[1] += bf_hi(v.x); sg[2] += bf_lo(v.y); sg[3] += bf_hi(v.y);
    u.x = (u.x + sdu * su[0]) * s; u.y = (u.y + sdu * su[1]) * s;
    u.z = (u.z + sdu * su[2]) * s; u.w = (u.w + sdu * su[3]) * s;
    p.x = (p.x + sdp * sp[0]) * s; p.y = (p.y + sdp * sp[1]) * s;
    p.z = (p.z + sdp * sp[2]) * s; p.w = (p.w + sdp * sp[3]) * s;
    g.x = (g.x + sdn * sg[0]) * s; g.y = (g.y + sdn * sg[1]) * s;
    g.z = (g.z + sdn * sg[2]) * s; g.w = (g.w + sdn * sg[3]) * s;
    float dp = u.x * p.x + u.y * p.y + u.z * p.z + u.w * p.w;
    float dn = u.x * g.x + u.y * g.y + u.z * g.z + u.w * g.w;
    float rg = u.x * u.x + u.y * u.y + u.z * u.z + u.w * u.w
             + p.x * p.x + p.y * p.y + p.z * p.z + p.w * p.w
             + g.x * g.x + g.y * g.y + g.z * g.z + g.w * g.w;
    #pragma unroll
    for (int m = 1; m <= 8; m <<= 1) {
      dp += __shfl_xor(dp, m);
      dn += __shfl_xor(dn, m);
      rg += __shfl_xor(rg, m);
    }
    if (q == 0) {
      float diff = dp - dn;
      accL -= fminf(diff, 0.0f) - log1pf(expf(-fabsf(diff)));
      accR += rg;
    }
  }
  accL += __shfl_xor(accL, 16); accR += __shfl_xor(accR, 16);
  accL += __shfl_xor(accL, 32); accR += __shfl_xor(accR, 32);
  if (lane == 0) { sL[wid] = accL; sR[wid] = accR; }
  __syncthreads();
  if (threadIdx.x == 0) {
    bpart[blockIdx.x] = sL[0] + sL[1] + sL[2] + sL[3];
    bpart[LOSS_BLOCKS + blockIdx.x] = sR[0] + sR[1] + sR[2] + sR[3];
    __threadfence();
    sDone = (atomicAdd(cnt, 1) == LOSS_BLOCKS - 1) ? 1 : 0;
  }
  __syncthreads();
  if (sDone && threadIdx.x < 64) {
    __threadfence();  // acquire: other blocks' bpart stores
    int ln = threadIdx.x;
    float l = bpart[ln] + bpart[ln + 64] + bpart[ln + 128] + bpart[ln + 192];
    float rr = bpart[LOSS_BLOCKS + ln] + bpart[LOSS_BLOCKS + ln + 64]
             + bpart[LOSS_BLOCKS + ln + 128] + bpart[LOSS_BLOCKS + ln + 192];
    for (int off = 32; off > 0; off >>= 1) {
      l += __shfl_down(l, off);
      rr += __shfl_down(rr, off);
    }
    if (ln == 0) out[0] = l * (1.0f / BB) + LW * 0.5f * rr * (1.0f / BB);
  }
}

extern "C" void kernel_launch(void* const* d_in, const int* in_sizes, int n_in,
                              void* d_out, int out_size, void* d_ws, size_t ws_size,
                              hipStream_t stream) {
  const float* Gu = (const float*)d_in[0];
  const float* Gi = (const float*)d_in[1];
  const int* eu  = (const int*)d_in[2];
  const int* ei  = (const int*)d_in[3];
  const int* usr = (const int*)d_in[4];
  const int* pos = (const int*)d_in[5];
  const int* neg = (const int*)d_in[6];
  float* out = (float*)d_out;

  // Workspace: ~8 MB ints + 9.6+9.6+19.2+19.2 MB h = ~66 MB.
  int* deg   = (int*)d_ws;                 // NN16
  int* cnt   = deg + NN16;                 // 16 (zeroed with deg via memset)
  int* ptr   = cnt + 16;                   // NN16
  int* blk   = ptr + NN16;                 // 1024
  int* ru    = blk + 1024;                 // E0
  int* ri    = ru + E0;                    // E0
  int* col   = ri + E0;                    // E2
  float* dinv = (float*)(col + E2);        // NN16
  unsigned* h0 = (unsigned*)(dinv + NN16); // NNODES*16 uints (fp8, 9.6 MB)
  unsigned* h1 = h0 + (size_t)NNODES * 16; // fp8, 9.6 MB
  uint2* h2  = (uint2*)(h1 + (size_t)NNODES * 16);  // bf16, 19.2 MB
  uint2* h3  = h2 + (size_t)NNODES * 16;            // bf16, 19.2 MB
  float* bpart = (float*)(h3 + (size_t)NNODES * 16);  // 2*LOSS_BLOCKS

  const int T = 256;
  auto cdiv = [](int a, int b) { return (a + b - 1) / b; };

  const float4* Gu4 = (const float4*)Gu;
  const float4* Gi4 = (const float4*)Gi;

  hipMemsetAsync(deg, 0, (size_t)(NN16 + 16) * sizeof(int), stream);
  k_count_deg<<<cdiv(E0, T), T, 0, stream>>>(eu, ei, deg, ru, ri);
  k_scan1<<<NB, 256, 0, stream>>>(deg, ptr, blk);
  k_scan_fix<<<NB, 256, 0, stream>>>(ptr, blk, deg, dinv);
  k_place_cast<<<PLACE_B + CAST_B, 256, 0, stream>>>(eu, ei, ptr, ru, ri, col,
                                                     Gu4, Gi4, dinv, h0);

  k_spmm2<true><<<UBLK + IBLK, 512, 0, stream>>>(ptr, deg, col, dinv,
                                                 (const uint2*)h0, (void*)h1);
  k_spmm2<false><<<UBLK + IBLK, 512, 0, stream>>>(ptr, deg, col, dinv,
                                                  (const uint2*)h1, (void*)h2);
  k_spmm_batch<<<(3 * BB) / 16, 512, 0, stream>>>(usr, pos, neg, ptr, deg, col, dinv,
                                                  (const uint4*)h2, (uint4*)h3);

  k_loss<<<LOSS_BLOCKS, 256, 0, stream>>>(usr, pos, neg, deg, Gu4, Gi4,
                                          h1, h2, h3, bpart, cnt, out);
}